// Round 6
// baseline (191.031 us; speedup 1.0000x reference)
//
#include <hip/hip_runtime.h>
#include <hip/hip_bf16.h>
#include <stdint.h>

#define WW    361            // spatial positions
#define CCH   64             // channels (K)
#define NP    368            // query rows padded to 23 tiles of 16
#define NBS   600            // B*S
#define NTHR  768            // 12 waves
#define NTILES 23            // 16-row support tiles (361 -> 23)
#define CHF   (8 * WW)       // floats per 8-channel chunk = 2888
#define CHF4  722            // float4s per chunk

typedef __attribute__((ext_vector_type(8))) short short8;
typedef __attribute__((ext_vector_type(4))) float f32x4;

union S8U { short8 v; unsigned int u[4]; uint4 q; };

__global__ __launch_bounds__(NTHR, 6) void cossim_max_kernel(
    const float* __restrict__ support, const float* __restrict__ query,
    float* __restrict__ out)
{
  // Q bf16 tile: row-major [m][k], pitch 128 B, 16B-chunk XOR swizzle
  // (elem (m,k) at m*64 + ((k/8 ^ (m&7))*8) + (k&7)) — R1/R4-proven conflict-free.
  __shared__ __align__(16) unsigned short Q_sh[NP * CCH];   // 47104 B
  // fp32 staging chunks, double-buffered, +16 floats zeroed pad (overflow reads)
  __shared__ __align__(16) float F_sh[2 * CHF + 16];        // 23168 B
  __shared__ float inv_q[NP];                               //  1472 B
  __shared__ float inv_s[NP];                               //  1472 B -> 73216 B total

  const int tid  = threadIdx.x;
  const int lane = tid & 63;
  const int wv   = tid >> 6;          // 0..11
  const int l15  = lane & 15;
  const int quad = lane >> 4;         // 0..3
  const int bs   = blockIdx.x;

  const float* sg = support + (size_t)bs * (WW * CCH);
  const float* qg = query   + (size_t)bs * (WW * CCH);

  // ---- init: zero Q pad rows, inv_q pads, F pad + F[1] head (t=0 overflow) ----
  if (tid < 56) ((uint4*)&Q_sh[361 * CCH])[tid] = make_uint4(0u, 0u, 0u, 0u);
  if (tid >= 56 && tid < 63) inv_q[361 + (tid - 56)] = 0.f;
  if (tid >= 64 && tid < 80) F_sh[2 * CHF + (tid - 64)] = 0.f;
  if (tid >= 80 && tid < 96) F_sh[CHF + (tid - 80)] = 0.f;

  // ---- pre-load chunk 0 (S channels 0..7) into buf 0: flat float4 copy ----
  if (wv >= 6) {
    const int lw = wv - 6;
    #pragma unroll
    for (int r = 0; r < 2; ++r) {
      const int f = 64 * (lw + 6 * r) + lane;
      if (f < CHF4) *(float4*)&F_sh[4 * f] = *(const float4*)(sg + 4 * f);
    }
  }
  __syncthreads();

  // A fragments (support) live in registers: af[tile 0/1][k-half]
  short8 af[2][2];
  {
    S8U z; z.q = make_uint4(0u, 0u, 0u, 0u);
    af[0][0] = z.v; af[0][1] = z.v; af[1][0] = z.v; af[1][1] = z.v;
  }
  float ssq_t[2] = {0.f, 0.f};   // per-tile S-norm partials (this lane's 16 k)
  float ssqq = 0.f;              // Q-norm accumulator (transposer threads)
  const int m0 = 32 * wv + l15;  // row of tile tt is m0 + 16*tt

  // ---- 16-chunk pipeline: chunks 0..7 = S (frag extract), 8..15 = Q (transpose) ----
  for (int t = 0; t < 16; ++t) {
    const int buf  = (t & 1) ? CHF : 0;
    const int nbuf = (t & 1) ? 0 : CHF;

    // (a) loaders issue next chunk's global loads (async; consumed after barrier)
    float4 ld[2];
    if (wv >= 6 && t < 15) {
      const int tn = t + 1;
      const float* gbase = (tn < 8 ? sg : qg) + (tn & 7) * CHF;
      const int lw = wv - 6;
      #pragma unroll
      for (int r = 0; r < 2; ++r) {
        const int f = 64 * (lw + 6 * r) + lane;
        if (f < CHF4) ld[r] = *(const float4*)(gbase + 4 * f);
      }
    }

    // (b) consume current chunk
    if (t < 8) {
      // S chunk t: channels/k = 8t..8t+7 -> serves quad (t&3), k-half (t>>2)
      if (quad == (t & 3)) {
        const int s = t >> 2;
        #pragma unroll
        for (int tt = 0; tt < 2; ++tt) {
          const int tile = 2 * wv + tt;
          if (tile < NTILES) {
            const int m = m0 + 16 * tt;
            float v[8];
            #pragma unroll
            for (int c = 0; c < 8; ++c) v[c] = F_sh[buf + c * WW + m];
            S8U p;
            float ss = 0.f;
            #pragma unroll
            for (int jj = 0; jj < 4; ++jj) {
              ss += v[2*jj] * v[2*jj] + v[2*jj+1] * v[2*jj+1];
              __hip_bfloat162 b2 =
                  __float22bfloat162_rn(make_float2(v[2*jj], v[2*jj+1]));
              p.u[jj] = *(unsigned int*)&b2;
            }
            af[tt][s] = p.v;
            ssq_t[tt] += ss;
          }
        }
      }
      if (t == 7) {
        // finalize inv_s: sum this row's partials across the 4 quads
        #pragma unroll
        for (int tt = 0; tt < 2; ++tt) {
          float s = ssq_t[tt];
          s += __shfl_xor(s, 16);
          s += __shfl_xor(s, 32);
          if (quad == 0 && (2 * wv + tt) < NTILES)
            inv_s[m0 + 16 * tt] = rsqrtf(s);
        }
      }
    } else {
      // Q chunk (t-8): thread m<361 transposes+converts its row slice
      const int cq = t - 8;
      if (tid < WW) {
        const int m = tid;
        float v[8];
        #pragma unroll
        for (int c = 0; c < 8; ++c) v[c] = F_sh[buf + c * WW + m];
        S8U p;
        #pragma unroll
        for (int jj = 0; jj < 4; ++jj) {
          ssqq += v[2*jj] * v[2*jj] + v[2*jj+1] * v[2*jj+1];
          __hip_bfloat162 b2 =
              __float22bfloat162_rn(make_float2(v[2*jj], v[2*jj+1]));
          p.u[jj] = *(unsigned int*)&b2;
        }
        *(uint4*)&Q_sh[m * CCH + ((cq ^ (m & 7)) * 8)] = p.q;
        if (t == 15) inv_q[m] = rsqrtf(ssqq);
      }
    }

    // (c) loaders store next chunk into the other buffer (waitcnt auto-inserted)
    if (wv >= 6 && t < 15) {
      const int lw = wv - 6;
      #pragma unroll
      for (int r = 0; r < 2; ++r) {
        const int f = 64 * (lw + 6 * r) + lane;
        if (f < CHF4) *(float4*)&F_sh[nbuf + 4 * f] = ld[r];
      }
    }
    __syncthreads();
  }

  // ---- Compute: wave wv owns tiles 2wv, 2wv+1; loop 23 p-tiles; B shared ----
  f32x4 mx0 = {-3e38f, -3e38f, -3e38f, -3e38f};
  f32x4 mx1 = {-3e38f, -3e38f, -3e38f, -3e38f};

  for (int pt = 0; pt < NP / 16; ++pt) {
    const int n  = 16 * pt + l15;
    const int sw = l15 & 7;                 // == n&7 (16*pt ≡ 0 mod 8)
    short8 b0 = *(const short8*)&Q_sh[n * CCH + (((0 + quad) ^ sw) * 8)];
    short8 b1 = *(const short8*)&Q_sh[n * CCH + (((4 + quad) ^ sw) * 8)];
    f32x4 acc0 = {0.f, 0.f, 0.f, 0.f};
    f32x4 acc1 = {0.f, 0.f, 0.f, 0.f};
    acc0 = __builtin_amdgcn_mfma_f32_16x16x32_bf16(af[0][0], b0, acc0, 0, 0, 0);
    acc0 = __builtin_amdgcn_mfma_f32_16x16x32_bf16(af[0][1], b1, acc0, 0, 0, 0);
    acc1 = __builtin_amdgcn_mfma_f32_16x16x32_bf16(af[1][0], b0, acc1, 0, 0, 0);
    acc1 = __builtin_amdgcn_mfma_f32_16x16x32_bf16(af[1][1], b1, acc1, 0, 0, 0);
    const float qs   = inv_q[n];
    const float bias = (n < WW) ? 0.f : -1e30f;  // pad p: acc*0 - 1e30 never wins
    #pragma unroll
    for (int r = 0; r < 4; ++r) {
      mx0[r] = fmaxf(mx0[r], acc0[r] * qs + bias);
      mx1[r] = fmaxf(mx1[r], acc1[r] * qs + bias);
    }
  }

  // max over query columns (col = lane&15): butterfly within 16-lane group.
  // fmaxf drops NaN operands, so garbage columns (m>360 of tile 22) are inert.
  #pragma unroll
  for (int d = 1; d < 16; d <<= 1) {
    #pragma unroll
    for (int r = 0; r < 4; ++r) {
      mx0[r] = fmaxf(mx0[r], __shfl_xor(mx0[r], d));
      mx1[r] = fmaxf(mx1[r], __shfl_xor(mx1[r], d));
    }
  }

  // D row = quad*4 + reg = support row within tile; one writer per 16-lane group
  if (l15 == 0) {
    #pragma unroll
    for (int tt = 0; tt < 2; ++tt) {
      if ((2 * wv + tt) < NTILES) {
        #pragma unroll
        for (int r = 0; r < 4; ++r) {
          const int mL = 32 * wv + 16 * tt + 4 * quad + r;
          if (mL < WW) {
            const float val = (tt == 0 ? mx0[r] : mx1[r]) * inv_s[mL];
            out[(size_t)bs * WW + mL] = val;
          }
        }
      }
    }
  }
}

extern "C" void kernel_launch(void* const* d_in, const int* in_sizes, int n_in,
                              void* d_out, int out_size, void* d_ws, size_t ws_size,
                              hipStream_t stream) {
  const float* support = (const float*)d_in[0];
  const float* query   = (const float*)d_in[1];
  float* out = (float*)d_out;
  dim3 grid(NBS), block(NTHR);
  hipLaunchKernelGGL(cossim_max_kernel, grid, block, 0, stream,
                     support, query, out);
}

// Round 7
// 143.745 us; speedup vs baseline: 1.3290x; 1.3290x over previous
//
#include <hip/hip_runtime.h>
#include <hip/hip_bf16.h>
#include <stdint.h>

#define WW     361            // spatial positions
#define CCH    64             // channels (K)
#define NP     368            // query rows padded to 23 tiles of 16
#define NBS    600            // B*S
#define NTHR   768            // 12 waves
#define NTILES 23             // 16-row support tiles
#define CHF    (8 * WW)       // floats per 8-channel chunk = 2888
#define CHF4   722            // float4s per chunk

typedef __attribute__((ext_vector_type(8))) short short8;
typedef __attribute__((ext_vector_type(4))) float f32x4;

union S8U { short8 v; unsigned int u[4]; uint4 q; };

__device__ __forceinline__ short8 pack8(const float* v, float& ssq) {
  S8U p;
  #pragma unroll
  for (int jj = 0; jj < 4; ++jj) {
    ssq += v[2*jj] * v[2*jj] + v[2*jj+1] * v[2*jj+1];
    __hip_bfloat162 b2 = __float22bfloat162_rn(make_float2(v[2*jj], v[2*jj+1]));
    p.u[jj] = *(unsigned int*)&b2;
  }
  return p.v;
}

__global__ __launch_bounds__(NTHR, 6) void cossim_max_kernel(
    const float* __restrict__ support, const float* __restrict__ query,
    float* __restrict__ out)
{
  // Q bf16 tile: [m][k], pitch 128B, 16B-chunk XOR swizzle (conflict-free, R1-R5)
  __shared__ __align__(16) unsigned short Q_sh[NP * CCH];   // 47104 B
  __shared__ __align__(16) float F_sh[2 * CHF + 16];        // 23168 B (dbuf + pad)
  __shared__ float inv_q[NP];                               //  1472 B
  __shared__ float inv_s[NP];                               //  1472 B -> 73216 B

  const int tid  = threadIdx.x;
  const int lane = tid & 63;
  const int wv   = tid >> 6;          // 0..11
  const int l15  = lane & 15;
  const int quad = lane >> 4;         // 0..3
  const int bs   = blockIdx.x;

  const float* sg = support + (size_t)bs * (WW * CCH);
  const float* qg = query   + (size_t)bs * (WW * CCH);

  // ---- init pads ----
  if (tid < 56) ((uint4*)&Q_sh[361 * CCH])[tid] = make_uint4(0u, 0u, 0u, 0u);
  if (tid >= 64 && tid < 71) inv_q[361 + (tid - 64)] = 0.f;
  if (tid >= 96 && tid < 112) F_sh[2 * CHF + (tid - 96)] = 0.f;

  // ---- preload chunk 0 (S channels 0..7) into buf 0: one float4 per thread ----
  if (tid < CHF4) *(float4*)&F_sh[4 * tid] = *(const float4*)(sg + 4 * tid);
  __syncthreads();

  // A fragments as NAMED registers (R6 lesson: any dynamic indexing -> scratch)
  short8 af00, af01, af10, af11;      // [tile 0/1][k-half 0/1]
  { S8U z; z.q = make_uint4(0u,0u,0u,0u); af00=z.v; af01=z.v; af10=z.v; af11=z.v; }
  float ss0 = 0.f, ss1 = 0.f;         // per-tile S-norm partials (this lane's 16 k)
  float ssqq = 0.f;                   // Q-norm accumulator (transposer threads)
  const int m0 = 32 * wv + l15;

  // ---- 16-chunk pipeline, FULLY UNROLLED: 0..7 = S (frag extract), 8..15 = Q ----
  #pragma unroll
  for (int t = 0; t < 16; ++t) {
    const int buf  = (t & 1) ? CHF : 0;
    const int nbuf = (t & 1) ? 0 : CHF;

    // (a) issue next chunk's load (1 float4/thread, 1 KB/wave-instr contiguous)
    float4 ld;
    if (t < 15 && tid < CHF4) {
      const float* src = ((t + 1) < 8 ? sg : qg) + ((t + 1) & 7) * CHF;
      ld = *(const float4*)(src + 4 * tid);
    }

    // (b) consume current chunk from LDS
    if (t < 8) {
      // S chunk t: channels 8t..8t+7 -> quad (t&3), k-half (t>>2). Static after unroll.
      if (quad == (t & 3)) {
        {
          float v[8];
          #pragma unroll
          for (int c = 0; c < 8; ++c) v[c] = F_sh[buf + c * WW + m0];
          short8 p = pack8(v, ss0);
          if ((t >> 2) == 0) af00 = p; else af01 = p;
        }
        if (2 * wv + 1 < NTILES) {
          float v[8];
          #pragma unroll
          for (int c = 0; c < 8; ++c) v[c] = F_sh[buf + c * WW + m0 + 16];
          short8 p = pack8(v, ss1);
          if ((t >> 2) == 0) af10 = p; else af11 = p;
        }
      }
      if (t == 7) {
        // finalize inv_s: sum row partials across the 4 quads
        float s0 = ss0, s1 = ss1;
        s0 += __shfl_xor(s0, 16); s0 += __shfl_xor(s0, 32);
        s1 += __shfl_xor(s1, 16); s1 += __shfl_xor(s1, 32);
        if (quad == 0) {
          inv_s[m0] = rsqrtf(s0);
          if (2 * wv + 1 < NTILES) inv_s[m0 + 16] = rsqrtf(s1);
        }
      }
    } else {
      // Q chunk (t-8): thread m<361 transposes+converts its row slice
      const int cq = t - 8;
      if (tid < WW) {
        const int m = tid;
        float v[8];
        #pragma unroll
        for (int c = 0; c < 8; ++c) v[c] = F_sh[buf + c * WW + m];
        S8U p; p.v = pack8(v, ssqq);
        *(uint4*)&Q_sh[m * CCH + ((cq ^ (m & 7)) * 8)] = p.q;
        if (t == 15) inv_q[m] = rsqrtf(ssqq);
      }
    }

    // (c) store next chunk into the other buffer
    if (t < 15 && tid < CHF4) *(float4*)&F_sh[nbuf + 4 * tid] = ld;
    __syncthreads();
  }

  // ---- Compute: wave wv owns tiles 2wv, 2wv+1; loop 23 p-tiles; B shared ----
  f32x4 mx0 = {-3e38f, -3e38f, -3e38f, -3e38f};
  f32x4 mx1 = {-3e38f, -3e38f, -3e38f, -3e38f};

  for (int pt = 0; pt < NP / 16; ++pt) {
    const int n  = 16 * pt + l15;
    const int sw = l15 & 7;                 // == n&7 (16*pt ≡ 0 mod 8)
    short8 b0 = *(const short8*)&Q_sh[n * CCH + (((0 + quad) ^ sw) * 8)];
    short8 b1 = *(const short8*)&Q_sh[n * CCH + (((4 + quad) ^ sw) * 8)];
    f32x4 acc0 = {0.f, 0.f, 0.f, 0.f};
    f32x4 acc1 = {0.f, 0.f, 0.f, 0.f};
    acc0 = __builtin_amdgcn_mfma_f32_16x16x32_bf16(af00, b0, acc0, 0, 0, 0);
    acc0 = __builtin_amdgcn_mfma_f32_16x16x32_bf16(af01, b1, acc0, 0, 0, 0);
    acc1 = __builtin_amdgcn_mfma_f32_16x16x32_bf16(af10, b0, acc1, 0, 0, 0);
    acc1 = __builtin_amdgcn_mfma_f32_16x16x32_bf16(af11, b1, acc1, 0, 0, 0);
    const float qs   = inv_q[n];
    const float bias = (n < WW) ? 0.f : -1e30f;  // pad p: acc==0 -> never wins
    #pragma unroll
    for (int r = 0; r < 4; ++r) {
      mx0[r] = fmaxf(mx0[r], acc0[r] * qs + bias);
      mx1[r] = fmaxf(mx1[r], acc1[r] * qs + bias);
    }
  }

  // max over query columns (col = lane&15): butterfly within 16-lane group.
  // Garbage support rows (m>360, tile 22) stay row-isolated in MFMA; not written.
  #pragma unroll
  for (int d = 1; d < 16; d <<= 1) {
    #pragma unroll
    for (int r = 0; r < 4; ++r) {
      mx0[r] = fmaxf(mx0[r], __shfl_xor(mx0[r], d));
      mx1[r] = fmaxf(mx1[r], __shfl_xor(mx1[r], d));
    }
  }

  // D row = quad*4 + reg; one writer lane per 16-lane group
  if (l15 == 0) {
    #pragma unroll
    for (int r = 0; r < 4; ++r) {
      const int mL0 = 32 * wv + 4 * quad + r;
      if (mL0 < WW) out[(size_t)bs * WW + mL0] = mx0[r] * inv_s[mL0];
      if (2 * wv + 1 < NTILES) {
        const int mL1 = 32 * wv + 16 + 4 * quad + r;
        if (mL1 < WW) out[(size_t)bs * WW + mL1] = mx1[r] * inv_s[mL1];
      }
    }
  }
}

extern "C" void kernel_launch(void* const* d_in, const int* in_sizes, int n_in,
                              void* d_out, int out_size, void* d_ws, size_t ws_size,
                              hipStream_t stream) {
  const float* support = (const float*)d_in[0];
  const float* query   = (const float*)d_in[1];
  float* out = (float*)d_out;
  dim3 grid(NBS), block(NTHR);
  hipLaunchKernelGGL(cossim_max_kernel, grid, block, 0, stream,
                     support, query, out);
}